// Round 4
// baseline (818.715 us; speedup 1.0000x reference)
//
#include <hip/hip_runtime.h>
#include <hip/hip_bf16.h>

typedef __attribute__((ext_vector_type(8))) short short8;
typedef __attribute__((ext_vector_type(4))) float floatx4;

#define B_ROWS 4096
#define N_COLS 8192
#define K_DIM  4096
#define INV_T  10.0f

// round-half-up fp32 -> bf16 pair pack
__device__ __forceinline__ unsigned pack2bf16(float a, float b) {
    unsigned lo = (__float_as_uint(a) + 0x8000u) >> 16;
    unsigned hi = (__float_as_uint(b) + 0x8000u) & 0xFFFF0000u;
    return lo | hi;
}

// async global->LDS, 16B per lane, LDS dest = wave-uniform base + lane*16
__device__ __forceinline__ void gload_lds16(const void* g, void* l) {
    __builtin_amdgcn_global_load_lds(
        (const __attribute__((address_space(1))) void*)g,
        (__attribute__((address_space(3))) void*)l,
        16, 0, 0);
}

// ---------------------------------------------------------------------------
// K0: convert im,s -> bf16 in ws; fused diag. Balanced: 6144 blocks,
// each moves ~32 KB read / 16 KB write.
//   bid < 4096        : im row bid + s row bid + dot -> diag
//   bid in [4096,6144): s rows 4096+2k, 4097+2k
// ---------------------------------------------------------------------------
__global__ __launch_bounds__(256) void convert_diag_kernel(
    const float* __restrict__ im, const float* __restrict__ s,
    const float* __restrict__ sims,
    unsigned short* __restrict__ im_b, unsigned short* __restrict__ s_b,
    float* __restrict__ diag)
{
    const int bid = blockIdx.x;
    if (bid < B_ROWS) {
        const int row = bid;
        const float4* arow = (const float4*)(im + (size_t)row * K_DIM);
        const float4* srow = (const float4*)(s  + (size_t)row * K_DIM);
        uint4* ab = (uint4*)(im_b + (size_t)row * K_DIM);
        uint4* sb = (uint4*)(s_b + (size_t)row * K_DIM);
        float sum = 0.f;
        #pragma unroll
        for (int ii = 0; ii < 2; ++ii) {
            const int i = threadIdx.x + ii * 256;
            float4 y0 = srow[2 * i], y1 = srow[2 * i + 1];
            float4 x0 = arow[2 * i], x1 = arow[2 * i + 1];
            sb[i] = make_uint4(pack2bf16(y0.x, y0.y), pack2bf16(y0.z, y0.w),
                               pack2bf16(y1.x, y1.y), pack2bf16(y1.z, y1.w));
            ab[i] = make_uint4(pack2bf16(x0.x, x0.y), pack2bf16(x0.z, x0.w),
                               pack2bf16(x1.x, x1.y), pack2bf16(x1.z, x1.w));
            sum += x0.x * y0.x + x0.y * y0.y + x0.z * y0.z + x0.w * y0.w;
            sum += x1.x * y1.x + x1.y * y1.y + x1.z * y1.z + x1.w * y1.w;
        }
        #pragma unroll
        for (int off = 1; off < 64; off <<= 1) sum += __shfl_xor(sum, off, 64);
        __shared__ float wsum[4];
        const int lane = threadIdx.x & 63, wid = threadIdx.x >> 6;
        if (lane == 0) wsum[wid] = sum;
        __syncthreads();
        if (threadIdx.x == 0) {
            float tot = wsum[0] + wsum[1] + wsum[2] + wsum[3];
            diag[row] = 0.5f * sims[(size_t)row * N_COLS + row] + 0.5f * tot;
        }
    } else {
        const int r0 = B_ROWS + 2 * (bid - B_ROWS);
        #pragma unroll
        for (int rr = 0; rr < 2; ++rr) {
            const int row = r0 + rr;
            const float4* srow = (const float4*)(s + (size_t)row * K_DIM);
            uint4* sb = (uint4*)(s_b + (size_t)row * K_DIM);
            #pragma unroll
            for (int ii = 0; ii < 2; ++ii) {
                const int i = threadIdx.x + ii * 256;
                float4 y0 = srow[2 * i], y1 = srow[2 * i + 1];
                sb[i] = make_uint4(pack2bf16(y0.x, y0.y), pack2bf16(y0.z, y0.w),
                                   pack2bf16(y1.x, y1.y), pack2bf16(y1.z, y1.w));
            }
        }
    }
}

// ---------------------------------------------------------------------------
// K1: bf16 MFMA GEMM, 128x128 tile, BK=32, global_load_lds width=16,
// XOR-swizzled LDS (verified conflict-free: SQ_LDS_BANK_CONFLICT=0 in r3),
// double-buffered prefetch, 4x4-supertile block swizzle for L3/L2 locality,
// fused loss epilogue.
// ---------------------------------------------------------------------------
__global__ __launch_bounds__(256, 4) void gemm_loss_bf16_kernel(
    const unsigned short* __restrict__ im_b, const unsigned short* __restrict__ s_b,
    const float* __restrict__ sims, const float* __restrict__ diag,
    float* __restrict__ pi2t_m, float* __restrict__ pi2t_l,
    float* __restrict__ pt2i_m, float* __restrict__ pt2i_l)
{
    // 1D grid 2048 -> 4x4 supertiles: consecutive 16 blocks form a 4 it x 4 jt
    // patch (4 A-tiles + 4 B-tiles resident together instead of 1 x 64).
    const int bid = blockIdx.x;
    const int sid = bid >> 4, sub = bid & 15;
    const int it = (sid >> 4) * 4 + (sub >> 2);   // 0..31
    const int jt = (sid & 15) * 4 + (sub & 3);    // 0..63

    const int tid = threadIdx.x;
    const int wid = tid >> 6, lane = tid & 63;
    const int wr = wid >> 1, wc = wid & 1;
    const int q = lane >> 4, cl = lane & 15;

    __shared__ __align__(16) unsigned short Asm[2][128 * 32];  // 2 x 8 KB
    __shared__ __align__(16) unsigned short Bsm[2][128 * 32];  // 2 x 8 KB
    __shared__ float sm_m[2][128], sm_l[2][128];
    __shared__ float sc_m[2][128], sc_l[2][128];

    const int r0 = (wid * 2 + 0) * 16 + (lane >> 2);
    const int r1 = (wid * 2 + 1) * 16 + (lane >> 2);
    const int kg = (((lane & 3) ^ ((lane >> 3) & 3))) * 8;   // swizzled k-offset
    const unsigned short* gA0 = im_b + (size_t)(it * 128 + r0) * K_DIM + kg;
    const unsigned short* gA1 = im_b + (size_t)(it * 128 + r1) * K_DIM + kg;
    const unsigned short* gB0 = s_b + (size_t)(jt * 128 + r0) * K_DIM + kg;
    const unsigned short* gB1 = s_b + (size_t)(jt * 128 + r1) * K_DIM + kg;
    const int lo0 = (wid * 2 + 0) * 512;
    const int lo1 = (wid * 2 + 1) * 512;

    const int swA = (q ^ ((cl >> 1) & 3)) * 8;
    int roffA[4], roffB[4];
    #pragma unroll
    for (int t = 0; t < 4; ++t) {
        roffA[t] = (wr * 64 + t * 16 + cl) * 32 + swA;
        roffB[t] = (wc * 64 + t * 16 + cl) * 32 + swA;
    }

    floatx4 acc[4][4];
    #pragma unroll
    for (int i = 0; i < 4; ++i)
        #pragma unroll
        for (int j = 0; j < 4; ++j) acc[i][j] = (floatx4){0.f, 0.f, 0.f, 0.f};

    // prefetch kt=0 into buffer 0
    gload_lds16(gA0, &Asm[0][lo0]);
    gload_lds16(gA1, &Asm[0][lo1]);
    gload_lds16(gB0, &Bsm[0][lo0]);
    gload_lds16(gB1, &Bsm[0][lo1]);
    gA0 += 32; gA1 += 32; gB0 += 32; gB1 += 32;

    for (int kt = 0; kt < 128; ++kt) {
        const int cur = kt & 1;
        __syncthreads();
        if (kt < 127) {
            const int nxt = cur ^ 1;
            gload_lds16(gA0, &Asm[nxt][lo0]);
            gload_lds16(gA1, &Asm[nxt][lo1]);
            gload_lds16(gB0, &Bsm[nxt][lo0]);
            gload_lds16(gB1, &Bsm[nxt][lo1]);
            gA0 += 32; gA1 += 32; gB0 += 32; gB1 += 32;
        }
        short8 av[4], bv[4];
        #pragma unroll
        for (int ty = 0; ty < 4; ++ty)
            av[ty] = *(const short8*)&Asm[cur][roffA[ty]];
        #pragma unroll
        for (int tx = 0; tx < 4; ++tx)
            bv[tx] = *(const short8*)&Bsm[cur][roffB[tx]];
        #pragma unroll
        for (int ty = 0; ty < 4; ++ty)
            #pragma unroll
            for (int tx = 0; tx < 4; ++tx)
                acc[ty][tx] = __builtin_amdgcn_mfma_f32_16x16x32_bf16(av[ty], bv[tx], acc[ty][tx], 0, 0, 0);
    }

    // ---------- fused epilogue (identical to verified rounds 1-3) ----------
    const int row_base = it * 128 + wr * 64;
    const int col_base = jt * 128 + wc * 64;
    const bool second_half = (jt >= 32);

    float dv[4][4];
    #pragma unroll
    for (int ty = 0; ty < 4; ++ty)
        #pragma unroll
        for (int r = 0; r < 4; ++r)
            dv[ty][r] = diag[row_base + ty * 16 + q * 4 + r];

    #pragma unroll
    for (int ty = 0; ty < 4; ++ty) {
        #pragma unroll
        for (int tx = 0; tx < 4; ++tx) {
            const int col = col_base + tx * 16 + cl;
            #pragma unroll
            for (int r = 0; r < 4; ++r) {
                const int row = row_base + ty * 16 + q * 4 + r;
                float v = 0.5f * sims[(size_t)row * N_COLS + col] + 0.5f * acc[ty][tx][r];
                if (second_half && v > dv[ty][r]) v = 0.f;
                acc[ty][tx][r] = v * INV_T;
            }
        }
    }

    #pragma unroll
    for (int ty = 0; ty < 4; ++ty) {
        #pragma unroll
        for (int r = 0; r < 4; ++r) {
            float mx = fmaxf(fmaxf(acc[ty][0][r], acc[ty][1][r]),
                             fmaxf(acc[ty][2][r], acc[ty][3][r]));
            #pragma unroll
            for (int off = 1; off < 16; off <<= 1) mx = fmaxf(mx, __shfl_xor(mx, off, 64));
            float sum = 0.f;
            #pragma unroll
            for (int tx = 0; tx < 4; ++tx) sum += __expf(acc[ty][tx][r] - mx);
            #pragma unroll
            for (int off = 1; off < 16; off <<= 1) sum += __shfl_xor(sum, off, 64);
            if (cl == 0) {
                sm_m[wc][wr * 64 + ty * 16 + q * 4 + r] = mx;
                sm_l[wc][wr * 64 + ty * 16 + q * 4 + r] = sum;
            }
        }
    }

    if (!second_half) {
        #pragma unroll
        for (int tx = 0; tx < 4; ++tx) {
            float mx = -3.4e38f;
            #pragma unroll
            for (int ty = 0; ty < 4; ++ty)
                #pragma unroll
                for (int r = 0; r < 4; ++r) mx = fmaxf(mx, acc[ty][tx][r]);
            mx = fmaxf(mx, __shfl_xor(mx, 16, 64));
            mx = fmaxf(mx, __shfl_xor(mx, 32, 64));
            float sum = 0.f;
            #pragma unroll
            for (int ty = 0; ty < 4; ++ty)
                #pragma unroll
                for (int r = 0; r < 4; ++r) sum += __expf(acc[ty][tx][r] - mx);
            sum += __shfl_xor(sum, 16, 64);
            sum += __shfl_xor(sum, 32, 64);
            if (q == 0) {
                sc_m[wr][wc * 64 + tx * 16 + cl] = mx;
                sc_l[wr][wc * 64 + tx * 16 + cl] = sum;
            }
        }
    }

    __syncthreads();

    if (tid < 128) {
        float m0 = sm_m[0][tid], m1 = sm_m[1][tid];
        float mm = fmaxf(m0, m1);
        float ll = sm_l[0][tid] * __expf(m0 - mm) + sm_l[1][tid] * __expf(m1 - mm);
        pi2t_m[(size_t)jt * B_ROWS + it * 128 + tid] = mm;
        pi2t_l[(size_t)jt * B_ROWS + it * 128 + tid] = ll;
    } else if (!second_half) {
        const int t2 = tid - 128;
        float m0 = sc_m[0][t2], m1 = sc_m[1][t2];
        float mm = fmaxf(m0, m1);
        float ll = sc_l[0][t2] * __expf(m0 - mm) + sc_l[1][t2] * __expf(m1 - mm);
        pt2i_m[(size_t)it * B_ROWS + jt * 128 + t2] = mm;
        pt2i_l[(size_t)it * B_ROWS + jt * 128 + t2] = ll;
    }
}

// ---------------------------------------------------------------------------
// Fallback path (round-1, fp32 inputs, in-kernel pack) — used if ws too small
// ---------------------------------------------------------------------------
__global__ __launch_bounds__(256) void diag_kernel(
    const float* __restrict__ im, const float* __restrict__ s,
    const float* __restrict__ sims, float* __restrict__ diag)
{
    const int row = blockIdx.x;
    const float4* a = (const float4*)(im + (size_t)row * K_DIM);
    const float4* b = (const float4*)(s  + (size_t)row * K_DIM);
    float sum = 0.f;
    for (int i = threadIdx.x; i < K_DIM / 4; i += 256) {
        float4 x = a[i], y = b[i];
        sum += x.x * y.x + x.y * y.y + x.z * y.z + x.w * y.w;
    }
    #pragma unroll
    for (int off = 1; off < 64; off <<= 1) sum += __shfl_xor(sum, off, 64);
    __shared__ float wsum[4];
    const int lane = threadIdx.x & 63, wid = threadIdx.x >> 6;
    if (lane == 0) wsum[wid] = sum;
    __syncthreads();
    if (threadIdx.x == 0) {
        float tot = wsum[0] + wsum[1] + wsum[2] + wsum[3];
        diag[row] = 0.5f * sims[(size_t)row * N_COLS + row] + 0.5f * tot;
    }
}

__global__ __launch_bounds__(256) void gemm_loss_kernel(
    const float* __restrict__ im, const float* __restrict__ s,
    const float* __restrict__ sims, const float* __restrict__ diag,
    float* __restrict__ pi2t_m, float* __restrict__ pi2t_l,
    float* __restrict__ pt2i_m, float* __restrict__ pt2i_l)
{
    const int jt = blockIdx.x;
    const int it = blockIdx.y;
    const int tid = threadIdx.x;
    const int wid = tid >> 6, lane = tid & 63;
    const int wr = wid >> 1, wc = wid & 1;
    const int q = lane >> 4, cl = lane & 15;

    __shared__ __align__(16) unsigned short Asm[128 * 32];
    __shared__ __align__(16) unsigned short Bsm[128 * 32];
    __shared__ float sm_m[2][128], sm_l[2][128];
    __shared__ float sc_m[2][128], sc_l[2][128];

    const int g0 = tid, g1 = tid + 256;
    const int r0 = g0 >> 2, c0 = (g0 & 3) * 8;
    const int r1 = g1 >> 2, c1 = (g1 & 3) * 8;
    const float* a0 = im + (size_t)(it * 128 + r0) * K_DIM + c0;
    const float* a1 = im + (size_t)(it * 128 + r1) * K_DIM + c1;
    const float* b0 = s  + (size_t)(jt * 128 + r0) * K_DIM + c0;
    const float* b1 = s  + (size_t)(jt * 128 + r1) * K_DIM + c1;
    const int la0 = r0 * 32 + c0, la1 = r1 * 32 + c1;

    floatx4 acc[4][4];
    #pragma unroll
    for (int i = 0; i < 4; ++i)
        #pragma unroll
        for (int j = 0; j < 4; ++j) acc[i][j] = (floatx4){0.f, 0.f, 0.f, 0.f};

    for (int kt = 0; kt < 128; ++kt) {
        float4 xa0 = *(const float4*)a0;
        float4 xa1 = *(const float4*)(a0 + 4);
        float4 ya0 = *(const float4*)a1;
        float4 ya1 = *(const float4*)(a1 + 4);
        float4 xb0 = *(const float4*)b0;
        float4 xb1 = *(const float4*)(b0 + 4);
        float4 yb0 = *(const float4*)b1;
        float4 yb1 = *(const float4*)(b1 + 4);
        a0 += 32; a1 += 32; b0 += 32; b1 += 32;
        __syncthreads();
        *(uint4*)&Asm[la0] = make_uint4(pack2bf16(xa0.x, xa0.y), pack2bf16(xa0.z, xa0.w),
                                        pack2bf16(xa1.x, xa1.y), pack2bf16(xa1.z, xa1.w));
        *(uint4*)&Asm[la1] = make_uint4(pack2bf16(ya0.x, ya0.y), pack2bf16(ya0.z, ya0.w),
                                        pack2bf16(ya1.x, ya1.y), pack2bf16(ya1.z, ya1.w));
        *(uint4*)&Bsm[la0] = make_uint4(pack2bf16(xb0.x, xb0.y), pack2bf16(xb0.z, xb0.w),
                                        pack2bf16(xb1.x, xb1.y), pack2bf16(xb1.z, xb1.w));
        *(uint4*)&Bsm[la1] = make_uint4(pack2bf16(yb0.x, yb0.y), pack2bf16(yb0.z, yb0.w),
                                        pack2bf16(yb1.x, yb1.y), pack2bf16(yb1.z, yb1.w));
        __syncthreads();
        short8 av[4], bv[4];
        #pragma unroll
        for (int ty = 0; ty < 4; ++ty)
            av[ty] = *(const short8*)&Asm[(wr * 64 + ty * 16 + cl) * 32 + q * 8];
        #pragma unroll
        for (int tx = 0; tx < 4; ++tx)
            bv[tx] = *(const short8*)&Bsm[(wc * 64 + tx * 16 + cl) * 32 + q * 8];
        #pragma unroll
        for (int ty = 0; ty < 4; ++ty)
            #pragma unroll
            for (int tx = 0; tx < 4; ++tx)
                acc[ty][tx] = __builtin_amdgcn_mfma_f32_16x16x32_bf16(av[ty], bv[tx], acc[ty][tx], 0, 0, 0);
    }

    const int row_base = it * 128 + wr * 64;
    const int col_base = jt * 128 + wc * 64;
    const bool second_half = (jt >= 32);

    float dv[4][4];
    #pragma unroll
    for (int ty = 0; ty < 4; ++ty)
        #pragma unroll
        for (int r = 0; r < 4; ++r)
            dv[ty][r] = diag[row_base + ty * 16 + q * 4 + r];

    #pragma unroll
    for (int ty = 0; ty < 4; ++ty) {
        #pragma unroll
        for (int tx = 0; tx < 4; ++tx) {
            const int col = col_base + tx * 16 + cl;
            #pragma unroll
            for (int r = 0; r < 4; ++r) {
                const int row = row_base + ty * 16 + q * 4 + r;
                float v = 0.5f * sims[(size_t)row * N_COLS + col] + 0.5f * acc[ty][tx][r];
                if (second_half && v > dv[ty][r]) v = 0.f;
                acc[ty][tx][r] = v * INV_T;
            }
        }
    }

    #pragma unroll
    for (int ty = 0; ty < 4; ++ty) {
        #pragma unroll
        for (int r = 0; r < 4; ++r) {
            float mx = fmaxf(fmaxf(acc[ty][0][r], acc[ty][1][r]),
                             fmaxf(acc[ty][2][r], acc[ty][3][r]));
            #pragma unroll
            for (int off = 1; off < 16; off <<= 1) mx = fmaxf(mx, __shfl_xor(mx, off, 64));
            float sum = 0.f;
            #pragma unroll
            for (int tx = 0; tx < 4; ++tx) sum += __expf(acc[ty][tx][r] - mx);
            #pragma unroll
            for (int off = 1; off < 16; off <<= 1) sum += __shfl_xor(sum, off, 64);
            if (cl == 0) {
                sm_m[wc][wr * 64 + ty * 16 + q * 4 + r] = mx;
                sm_l[wc][wr * 64 + ty * 16 + q * 4 + r] = sum;
            }
        }
    }

    if (!second_half) {
        #pragma unroll
        for (int tx = 0; tx < 4; ++tx) {
            float mx = -3.4e38f;
            #pragma unroll
            for (int ty = 0; ty < 4; ++ty)
                #pragma unroll
                for (int r = 0; r < 4; ++r) mx = fmaxf(mx, acc[ty][tx][r]);
            mx = fmaxf(mx, __shfl_xor(mx, 16, 64));
            mx = fmaxf(mx, __shfl_xor(mx, 32, 64));
            float sum = 0.f;
            #pragma unroll
            for (int ty = 0; ty < 4; ++ty)
                #pragma unroll
                for (int r = 0; r < 4; ++r) sum += __expf(acc[ty][tx][r] - mx);
            sum += __shfl_xor(sum, 16, 64);
            sum += __shfl_xor(sum, 32, 64);
            if (q == 0) {
                sc_m[wr][wc * 64 + tx * 16 + cl] = mx;
                sc_l[wr][wc * 64 + tx * 16 + cl] = sum;
            }
        }
    }

    __syncthreads();

    if (tid < 128) {
        float m0 = sm_m[0][tid], m1 = sm_m[1][tid];
        float mm = fmaxf(m0, m1);
        float ll = sm_l[0][tid] * __expf(m0 - mm) + sm_l[1][tid] * __expf(m1 - mm);
        pi2t_m[(size_t)jt * B_ROWS + it * 128 + tid] = mm;
        pi2t_l[(size_t)jt * B_ROWS + it * 128 + tid] = ll;
    } else if (!second_half) {
        const int t2 = tid - 128;
        float m0 = sc_m[0][t2], m1 = sc_m[1][t2];
        float mm = fmaxf(m0, m1);
        float ll = sc_l[0][t2] * __expf(m0 - mm) + sc_l[1][t2] * __expf(m1 - mm);
        pt2i_m[(size_t)it * B_ROWS + jt * 128 + t2] = mm;
        pt2i_l[(size_t)it * B_ROWS + jt * 128 + t2] = ll;
    }
}

// ---------------------------------------------------------------------------
// K2: merge partials -> per-row/per-col lse terms, block-reduce,
// atomicAdd scaled contribution into d_out (memset to 0 beforehand).
// ---------------------------------------------------------------------------
__global__ __launch_bounds__(256) void combine_kernel(
    const float* __restrict__ pi2t_m, const float* __restrict__ pi2t_l,
    const float* __restrict__ pt2i_m, const float* __restrict__ pt2i_l,
    const float* __restrict__ diag, float* __restrict__ out)
{
    const int gid = blockIdx.x * 256 + threadIdx.x;  // 0..8191
    float term;
    if (gid < B_ROWS) {
        const int row = gid;
        float m = pi2t_m[row], l = pi2t_l[row];
        for (int ct = 1; ct < 64; ++ct) {
            float m2 = pi2t_m[(size_t)ct * B_ROWS + row];
            float l2 = pi2t_l[(size_t)ct * B_ROWS + row];
            float nm = fmaxf(m, m2);
            l = l * __expf(m - nm) + l2 * __expf(m2 - nm);
            m = nm;
        }
        term = m + __logf(l) - diag[row] * INV_T;
    } else {
        const int col = gid - B_ROWS;
        float m = pt2i_m[col], l = pt2i_l[col];
        for (int rt = 1; rt < 32; ++rt) {
            float m2 = pt2i_m[(size_t)rt * B_ROWS + col];
            float l2 = pt2i_l[(size_t)rt * B_ROWS + col];
            float nm = fmaxf(m, m2);
            l = l * __expf(m - nm) + l2 * __expf(m2 - nm);
            m = nm;
        }
        term = m + __logf(l) - diag[col] * INV_T;
    }
    #pragma unroll
    for (int off = 1; off < 64; off <<= 1) term += __shfl_xor(term, off, 64);
    __shared__ float bsum[4];
    if ((threadIdx.x & 63) == 0) bsum[threadIdx.x >> 6] = term;
    __syncthreads();
    if (threadIdx.x == 0)
        atomicAdd(out, (bsum[0] + bsum[1] + bsum[2] + bsum[3]) * (1.0f / 4096.0f));
}

extern "C" void kernel_launch(void* const* d_in, const int* in_sizes, int n_in,
                              void* d_out, int out_size, void* d_ws, size_t ws_size,
                              hipStream_t stream)
{
    const float* im   = (const float*)d_in[0];   // [4096, 4096]
    const float* s    = (const float*)d_in[1];   // [8192, 4096]
    const float* sims = (const float*)d_in[2];   // [4096, 8192]
    float* out = (float*)d_out;

    const size_t im_b_bytes = (size_t)B_ROWS * K_DIM * 2;   // 32 MB
    const size_t s_b_bytes  = (size_t)N_COLS * K_DIM * 2;   // 64 MB
    const size_t f32_bytes  = (4096 + 2 * 64 * 4096 + 2 * 32 * 4096) * sizeof(float);
    const size_t need = im_b_bytes + s_b_bytes + f32_bytes;

    hipMemsetAsync(out, 0, sizeof(float), stream);

    if (ws_size >= need) {
        unsigned short* im_b = (unsigned short*)d_ws;
        unsigned short* s_b  = (unsigned short*)((char*)d_ws + im_b_bytes);
        float* fbase  = (float*)((char*)d_ws + im_b_bytes + s_b_bytes);
        float* diag   = fbase;
        float* pi2t_m = diag + 4096;
        float* pi2t_l = pi2t_m + 64 * 4096;
        float* pt2i_m = pi2t_l + 64 * 4096;
        float* pt2i_l = pt2i_m + 32 * 4096;

        convert_diag_kernel<<<6144, 256, 0, stream>>>(im, s, sims, im_b, s_b, diag);
        gemm_loss_bf16_kernel<<<2048, 256, 0, stream>>>(im_b, s_b, sims, diag,
                                                        pi2t_m, pi2t_l, pt2i_m, pt2i_l);
        combine_kernel<<<32, 256, 0, stream>>>(pi2t_m, pi2t_l, pt2i_m, pt2i_l, diag, out);
    } else {
        float* ws = (float*)d_ws;
        float* diag   = ws;
        float* pi2t_m = diag + 4096;
        float* pi2t_l = pi2t_m + 64 * 4096;
        float* pt2i_m = pi2t_l + 64 * 4096;
        float* pt2i_l = pt2i_m + 32 * 4096;

        diag_kernel<<<4096, 256, 0, stream>>>(im, s, sims, diag);
        gemm_loss_kernel<<<dim3(64, 32), 256, 0, stream>>>(im, s, sims, diag,
                                                           pi2t_m, pi2t_l, pt2i_m, pt2i_l);
        combine_kernel<<<32, 256, 0, stream>>>(pi2t_m, pi2t_l, pt2i_m, pt2i_l, diag, out);
    }
}